// Round 4
// baseline (374.490 us; speedup 1.0000x reference)
//
#include <hip/hip_runtime.h>

// BilinearSampler: img [B,H,W,C] f32, x_s/y_s [B,H,W] f32 in [-1,1] -> out [B,H,W,C] f32
// B=16, H=256, W=256, C=32.
//
// History:
// R3: direct gather, 8 thr/pixel, 4 px-groups pipelined. 88.5 us, FETCH 221 MB.
// R4 (REVERTED): XCD swizzle. FETCH 157 MB but 105 us -> bytes not the wall.
// R5 (REVERTED): forced MLP 2.6x. dur unchanged -> latency-hiding not the wall.
// R6 (REVERTED): nontemporal gathers. FETCH 248 MB, 105 us -> L2/L3 reuse of
//     texel lines was real; bypassing allocation hurts. Conclusion: the wall
//     is the random-128B-line request stream itself (4 per pixel, 5M lines).
// R7: ALGORITHMIC - binned LDS gather. Bin pixels by sampled 16x16-texel tile
//     (4096 bins); one WG per bin stages the 17x17-texel tile (37 KB LDS)
//     sequentially, serves all 4 corners from LDS. Random global gathers
//     eliminated; global traffic ~330 MB mostly-streaming.
//     hist -> scan -> scatter -> gather. Fallback to R3 kernel if ws too small.

constexpr int Bn = 16;
constexpr int Hn = 256;
constexpr int Wn = 256;
constexpr int Cn = 32;
constexpr int CG = Cn / 4;            // 8 float4 groups per pixel
constexpr int NPIX = Bn * Hn * Wn;    // 1,048,576
constexpr int TS = 16;                // bin tile size (texels)
constexpr int TH = TS + 1;            // staged width incl +1 halo
constexpr int NB = Bn * (Hn / TS) * (Wn / TS);   // 4096 bins

typedef float f4 __attribute__((ext_vector_type(4)));

// ws layout (16B-aligned chunks)
constexpr size_t WS_CNT  = 0;                          // u32 cnt[NB]
constexpr size_t WS_OFF  = 16 * 1024;                  // u32 off[NB]
constexpr size_t WS_CUR  = 32 * 1024;                  // u32 cur[NB]
constexpr size_t WS_IDS  = 48 * 1024;                  // u32 ids[NPIX]
constexpr size_t WS_XY   = WS_IDS + (size_t)NPIX * 4;  // float2 xy[NPIX]
constexpr size_t WS_NEED = WS_XY + (size_t)NPIX * 8;   // ~12.6 MB

// ---------------- pass 1: histogram ----------------
__global__ __launch_bounds__(256) void hist_k(
    const float* __restrict__ xs, const float* __restrict__ ys,
    unsigned* __restrict__ cnt)
{
    const int i = (blockIdx.x * 256 + threadIdx.x) * 4;
    const f4 xv = *(const f4*)(xs + i);
    const f4 yv = *(const f4*)(ys + i);
    const int b = i >> 16;   // H*W = 65536
#pragma unroll
    for (int j = 0; j < 4; ++j) {
        const float x = 0.5f * (xv[j] + 1.0f) * (float)(Wn - 1);
        const float y = 0.5f * (yv[j] + 1.0f) * (float)(Hn - 1);
        int x0 = (int)floorf(x);
        int y0 = (int)floorf(y);
        x0 = min(max(x0, 0), Wn - 1);
        y0 = min(max(y0, 0), Hn - 1);
        const int bin = (b << 8) + ((y0 >> 4) << 4) + (x0 >> 4);
        atomicAdd(&cnt[bin], 1u);
    }
}

// ---------------- pass 2: exclusive scan over 4096 bins ----------------
__global__ __launch_bounds__(1024) void scan_k(
    const unsigned* __restrict__ cnt,
    unsigned* __restrict__ off, unsigned* __restrict__ cur)
{
    __shared__ unsigned sc[1024];
    const int t = threadIdx.x;
    const uint4 c = ((const uint4*)cnt)[t];
    const unsigned s = c.x + c.y + c.z + c.w;
    sc[t] = s;
    __syncthreads();
    for (int d = 1; d < 1024; d <<= 1) {
        const unsigned v = (t >= d) ? sc[t - d] : 0u;
        __syncthreads();
        sc[t] += v;
        __syncthreads();
    }
    const unsigned excl = sc[t] - s;
    uint4 o;
    o.x = excl;
    o.y = o.x + c.x;
    o.z = o.y + c.y;
    o.w = o.z + c.z;
    ((uint4*)off)[t] = o;
    ((uint4*)cur)[t] = o;
}

// ---------------- pass 3: scatter pixel ids + coords ----------------
__global__ __launch_bounds__(256) void scat_k(
    const float* __restrict__ xs, const float* __restrict__ ys,
    unsigned* __restrict__ cur, unsigned* __restrict__ ids,
    float2* __restrict__ xy)
{
    const int i = (blockIdx.x * 256 + threadIdx.x) * 4;
    const f4 xv = *(const f4*)(xs + i);
    const f4 yv = *(const f4*)(ys + i);
    const int b = i >> 16;
#pragma unroll
    for (int j = 0; j < 4; ++j) {
        const float x = 0.5f * (xv[j] + 1.0f) * (float)(Wn - 1);
        const float y = 0.5f * (yv[j] + 1.0f) * (float)(Hn - 1);
        int x0 = (int)floorf(x);
        int y0 = (int)floorf(y);
        x0 = min(max(x0, 0), Wn - 1);
        y0 = min(max(y0, 0), Hn - 1);
        const int bin = (b << 8) + ((y0 >> 4) << 4) + (x0 >> 4);
        const unsigned pos = atomicAdd(&cur[bin], 1u);
        ids[pos] = (unsigned)(i + j);
        xy[pos] = make_float2(xv[j], yv[j]);
    }
}

// ---------------- pass 4: staged LDS gather ----------------
__global__ __launch_bounds__(256) void gather_k(
    const float* __restrict__ img,
    const unsigned* __restrict__ cnt, const unsigned* __restrict__ off,
    const unsigned* __restrict__ ids, const float2* __restrict__ xy,
    float* __restrict__ out)
{
    const int bin = blockIdx.x;
    const unsigned npix = cnt[bin];
    if (npix == 0u) return;
    const unsigned base = off[bin];
    const int b  = bin >> 8;
    const int ty = (bin >> 4) & 15;
    const int tx = bin & 15;

    __shared__ float tile[TH * TH * Cn];   // 17*17*32 f32 = 36,992 B

    const float* imgb = img + (size_t)b * (size_t)(Hn * Wn * Cn);
    const int tid = threadIdx.x;

    // stage 17x17 texels (clamped at image edge), coalesced by row segment
    for (int k = tid; k < TH * TH * (Cn / 4); k += 256) {
        const int r = k / (TH * (Cn / 4));
        const int m = k - r * (TH * (Cn / 4));
        const int c = m >> 3;
        const int q = m & 7;
        const int gy = min(ty * TS + r, Hn - 1);
        const int gx = min(tx * TS + c, Wn - 1);
        const f4 v = *(const f4*)(imgb + ((size_t)(gy * Wn + gx)) * Cn + q * 4);
        *(f4*)&tile[(r * TH + c) * Cn + q * 4] = v;
    }
    __syncthreads();

    const int slot = tid >> 3;   // 32 pixel slots
    const int cg   = tid & 7;    // float4 channel group

    for (unsigned i = slot; i < npix; i += 32) {
        const unsigned pos = base + i;
        const unsigned pix = ids[pos];
        const float2 cxy = xy[pos];

        const float x = 0.5f * (cxy.x + 1.0f) * (float)(Wn - 1);
        const float y = 0.5f * (cxy.y + 1.0f) * (float)(Hn - 1);
        const int x0 = (int)floorf(x);
        const int y0 = (int)floorf(y);
        const int x0c = min(max(x0, 0), Wn - 1);
        const int x1c = min(x0 + 1, Wn - 1);
        const int y0c = min(max(y0, 0), Hn - 1);
        const int y1c = min(y0 + 1, Hn - 1);

        const float wx1 = (float)x1c - x;
        const float wx0 = x - (float)x0c;
        const float wy1 = (float)y1c - y;
        const float wy0 = y - (float)y0c;

        const float wa = wx1 * wy1;
        const float wb = wx1 * wy0;
        const float wc = wx0 * wy1;
        const float wd = wx0 * wy0;

        // local tile coords (bin guarantees x0c>>4 == tx, y0c>>4 == ty)
        const int lx0 = x0c - tx * TS;
        const int lx1 = x1c - tx * TS;   // <= 16 (halo)
        const int ly0 = y0c - ty * TS;
        const int ly1 = y1c - ty * TS;

        const f4 va = *(const f4*)&tile[(ly0 * TH + lx0) * Cn + cg * 4];
        const f4 vb = *(const f4*)&tile[(ly1 * TH + lx0) * Cn + cg * 4];
        const f4 vc = *(const f4*)&tile[(ly0 * TH + lx1) * Cn + cg * 4];
        const f4 vd = *(const f4*)&tile[(ly1 * TH + lx1) * Cn + cg * 4];

        f4 o;
        o.x = wa * va.x + wb * vb.x + wc * vc.x + wd * vd.x;
        o.y = wa * va.y + wb * vb.y + wc * vc.y + wd * vd.y;
        o.z = wa * va.z + wb * vb.z + wc * vc.z + wd * vd.z;
        o.w = wa * va.w + wb * vb.w + wc * vc.w + wd * vd.w;

        f4* op = (f4*)out + (size_t)pix * CG + cg;
        __builtin_nontemporal_store(o, op);
    }
}

// ---------------- fallback: R3 direct-gather kernel ----------------
constexpr int NP = 4;

__global__ __launch_bounds__(256) void bilinear_kernel(
    const float* __restrict__ img,
    const float* __restrict__ xs,
    const float* __restrict__ ys,
    float* __restrict__ out)
{
    const int tid = threadIdx.x;
    const int cg  = tid & 7;
    const int lp  = tid >> 3;
    const int base_pix = blockIdx.x * 128 + lp;

    int pix[NP];
    float xsv[NP], ysv[NP];
#pragma unroll
    for (int g = 0; g < NP; ++g) {
        pix[g] = base_pix + g * 32;
        xsv[g] = __builtin_nontemporal_load(xs + pix[g]);
        ysv[g] = __builtin_nontemporal_load(ys + pix[g]);
    }

    float wa[NP], wb[NP], wc[NP], wd[NP];
    const f4* pa[NP];
    const f4* pb[NP];
    const f4* pc[NP];
    const f4* pd[NP];

#pragma unroll
    for (int g = 0; g < NP; ++g) {
        const float x = 0.5f * (xsv[g] + 1.0f) * (float)(Wn - 1);
        const float y = 0.5f * (ysv[g] + 1.0f) * (float)(Hn - 1);
        const int x0 = (int)floorf(x);
        const int y0 = (int)floorf(y);
        const int x0c = min(max(x0, 0), Wn - 1);
        const int x1c = min(max(x0 + 1, 0), Wn - 1);
        const int y0c = min(max(y0, 0), Hn - 1);
        const int y1c = min(max(y0 + 1, 0), Hn - 1);
        const float wx1 = (float)x1c - x;
        const float wx0 = x - (float)x0c;
        const float wy1 = (float)y1c - y;
        const float wy0 = y - (float)y0c;
        wa[g] = wx1 * wy1;
        wb[g] = wx1 * wy0;
        wc[g] = wx0 * wy1;
        wd[g] = wx0 * wy0;
        const int b = pix[g] >> 16;
        const size_t imgbase = (size_t)b * (size_t)(Hn * Wn * Cn);
        pa[g] = (const f4*)(img + imgbase + ((size_t)(y0c * Wn + x0c)) * Cn) + cg;
        pb[g] = (const f4*)(img + imgbase + ((size_t)(y1c * Wn + x0c)) * Cn) + cg;
        pc[g] = (const f4*)(img + imgbase + ((size_t)(y0c * Wn + x1c)) * Cn) + cg;
        pd[g] = (const f4*)(img + imgbase + ((size_t)(y1c * Wn + x1c)) * Cn) + cg;
    }

    f4 va[NP], vb[NP], vc[NP], vd[NP];
#pragma unroll
    for (int g = 0; g < NP; ++g) {
        va[g] = *pa[g];
        vb[g] = *pb[g];
        vc[g] = *pc[g];
        vd[g] = *pd[g];
    }

#pragma unroll
    for (int g = 0; g < NP; ++g) {
        f4 o;
        o.x = wa[g] * va[g].x + wb[g] * vb[g].x + wc[g] * vc[g].x + wd[g] * vd[g].x;
        o.y = wa[g] * va[g].y + wb[g] * vb[g].y + wc[g] * vc[g].y + wd[g] * vd[g].y;
        o.z = wa[g] * va[g].z + wb[g] * vb[g].z + wc[g] * vc[g].z + wd[g] * vd[g].z;
        o.w = wa[g] * va[g].w + wb[g] * vb[g].w + wc[g] * vc[g].w + wd[g] * vd[g].w;
        f4* op = (f4*)out + (size_t)pix[g] * CG + cg;
        __builtin_nontemporal_store(o, op);
    }
}

extern "C" void kernel_launch(void* const* d_in, const int* in_sizes, int n_in,
                              void* d_out, int out_size, void* d_ws, size_t ws_size,
                              hipStream_t stream)
{
    const float* img = (const float*)d_in[0];
    const float* xs  = (const float*)d_in[1];
    const float* ys  = (const float*)d_in[2];
    float* out       = (float*)d_out;

    if (ws_size < WS_NEED || d_ws == nullptr) {
        // fallback: direct gather (proven 88.5 us)
        bilinear_kernel<<<NPIX / 128, 256, 0, stream>>>(img, xs, ys, out);
        return;
    }

    char* ws = (char*)d_ws;
    unsigned* cnt = (unsigned*)(ws + WS_CNT);
    unsigned* off = (unsigned*)(ws + WS_OFF);
    unsigned* cur = (unsigned*)(ws + WS_CUR);
    unsigned* ids = (unsigned*)(ws + WS_IDS);
    float2*   xy  = (float2*)(ws + WS_XY);

    hipMemsetAsync(cnt, 0, NB * sizeof(unsigned), stream);

    const int cblocks = NPIX / (256 * 4);   // 1024
    hist_k<<<cblocks, 256, 0, stream>>>(xs, ys, cnt);
    scan_k<<<1, 1024, 0, stream>>>(cnt, off, cur);
    scat_k<<<cblocks, 256, 0, stream>>>(xs, ys, cur, ids, xy);
    gather_k<<<NB, 256, 0, stream>>>(img, cnt, off, ids, xy, out);
}